// Round 4
// baseline (1128.521 us; speedup 1.0000x reference)
//
#include <hip/hip_runtime.h>
#include <math.h>

#define NB 16    // batch
#define SS 256   // spatial size (H = W = 256)
#define DV 32    // channels
#define MM 12    // w-dim (j) modes kept
#define MK 24    // h-dim (iy) modes kept (0..11 and 244..255)
#define LL 4     // layers
#define TWO_PI_N 0.024543692606170259679f   // 2*pi/256

// Workspace (floats):
//   h   : [NB][DV][SS][SS]            134 MB, in-place per layer
//   A   : [NB][MM][DV][SS(iy)][2]     12.6 MB  (row-DFT of h)
//   F   : [NB][MM][DV][MK][2]          1.2 MB  (mixed spectral coeffs, pre-scaled)
//   twT : [SS][MM][2]                  24 KB   (cos, -sin) for the forward row DFT

// ------------------------------------------------------------- twiddle init
__global__ __launch_bounds__(256) void k_twinit(float* __restrict__ twT)
{
    int j = threadIdx.x;
    #pragma unroll
    for (int k = 0; k < MM; ++k) {
        float ang = TWO_PI_N * (float)((k * j) & 255);
        float s, c; sincosf(ang, &s, &c);
        twT[j * (MM * 2) + 2 * k]     = c;
        twT[j * (MM * 2) + 2 * k + 1] = -s;
    }
}

// ---------------------------------------------------------------- lifting
__global__ __launch_bounds__(256) void k_lift(const float* __restrict__ x,
        const float* __restrict__ p_w, const float* __restrict__ p_b,
        float* __restrict__ h)
{
    int tid = threadIdx.x;
    int b = blockIdx.x >> 8, iy = blockIdx.x & 255;
    float xv = x[((size_t)b * SS + iy) * SS + tid];
    float gy = -1.f + 2.f * (float)iy  * (1.f / 255.f);
    float gx = -1.f + 2.f * (float)tid * (1.f / 255.f);
    float* hb = h + ((size_t)b * DV * SS + iy) * SS + tid;
    #pragma unroll
    for (int c = 0; c < DV; ++c)
        hb[(size_t)c * SS * SS] = p_w[3*c] * xv + p_w[3*c+1] * gy
                                + p_w[3*c+2] * gx + p_b[c];
}

// ------------------------------------------------- forward row (j) DFT, 12 modes
// block = (b,c); lane = iy; thread owns its entire row in the j-loop.
// Twiddles come from the global table with a block-uniform index -> the
// compiler scalarizes these to s_load (K$), so the loop is pure v_fmac(s,v).
__global__ __launch_bounds__(256) void k_rowdft(const float* __restrict__ h,
        const float* __restrict__ twT, float* __restrict__ A)
{
    int tid = threadIdx.x;
    int b = blockIdx.x >> 5, c = blockIdx.x & 31;

    const float4* hr = (const float4*)(h + ((size_t)blockIdx.x * SS + tid) * SS);
    float ar[MM], ai[MM];
    #pragma unroll
    for (int k = 0; k < MM; ++k) { ar[k] = 0.f; ai[k] = 0.f; }

    #pragma unroll 2
    for (int j4 = 0; j4 < 64; ++j4) {
        float4 v = hr[j4];
        float vv[4] = {v.x, v.y, v.z, v.w};
        #pragma unroll
        for (int u = 0; u < 4; ++u) {
            const float* twj = twT + (size_t)(4 * j4 + u) * (MM * 2);  // uniform
            float vu = vv[u];
            #pragma unroll
            for (int k = 0; k < MM; ++k) {
                ar[k] += vu * twj[2 * k];
                ai[k] += vu * twj[2 * k + 1];
            }
        }
    }
    #pragma unroll
    for (int ky = 0; ky < MM; ++ky) {
        size_t o = ((((size_t)b * MM + ky) * DV + c) * SS + tid) * 2;
        float2 val; val.x = ar[ky]; val.y = ai[ky];
        *(float2*)&A[o] = val;                      // coalesced over iy
    }
}

// --------------------------- kx (iy) DFT + complex channel mix -> F (pre-scaled)
// block = (b,ky). Phase 1: thread = (c, m-set of 3), register phasors with
// LDS-table re-anchor every 64 steps. Phase 2: mix over 32 input channels.
__global__ __launch_bounds__(256) void k_mix(const float* __restrict__ A,
        const float* __restrict__ w1r, const float* __restrict__ w1i,
        const float* __restrict__ w2r, const float* __restrict__ w2i,
        float* __restrict__ F, int l)
{
    __shared__ float twcs[SS * 2];             // (cos, sin) of +2*pi*t/256
    __shared__ float Fin[DV][MK * 2 + 2];
    int tid = threadIdx.x;
    int b = blockIdx.x / MM, ky = blockIdx.x % MM;
    {
        float ang = TWO_PI_N * (float)tid;
        float s, c; sincosf(ang, &s, &c);
        twcs[2 * tid] = c; twcs[2 * tid + 1] = s;
    }
    __syncthreads();

    int c = tid >> 3, set = tid & 7;
    const float2* Ap = (const float2*)(A + ((((size_t)b * MM + ky) * DV + c) * SS) * 2);

    float fr[3], fi[3], pc[3], ps[3], sc[3], ssn[3];
    int f[3];
    #pragma unroll
    for (int k = 0; k < 3; ++k) {
        int m = set + 8 * k;
        f[k] = (m < MM) ? m : (232 + m);       // 244..255 for m >= 12
        sc[k] = twcs[2 * f[k]]; ssn[k] = twcs[2 * f[k] + 1];
        fr[k] = fi[k] = 0.f; pc[k] = 1.f; ps[k] = 0.f;
    }
    for (int iy = 0; iy < SS; ++iy) {
        if ((iy & 63) == 0) {                  // re-anchor: kills phasor drift
            #pragma unroll
            for (int k = 0; k < 3; ++k) {
                int t = (f[k] * iy) & 255;
                pc[k] = twcs[2 * t]; ps[k] = twcs[2 * t + 1];
            }
        }
        float2 a = Ap[iy];
        #pragma unroll
        for (int k = 0; k < 3; ++k) {
            fr[k] += a.x * pc[k] + a.y * ps[k];   // A * e^{-i th}
            fi[k] += a.y * pc[k] - a.x * ps[k];
            float np = pc[k] * sc[k] - ps[k] * ssn[k];
            float nq = pc[k] * ssn[k] + ps[k] * sc[k];
            pc[k] = np; ps[k] = nq;
        }
    }
    #pragma unroll
    for (int k = 0; k < 3; ++k) {
        int m = set + 8 * k;
        Fin[c][2 * m] = fr[k]; Fin[c][2 * m + 1] = fi[k];
    }
    __syncthreads();

    int o = c;
    float scale = ((ky == 0) ? 1.0f : 2.0f) * (1.0f / 65536.0f);
    #pragma unroll
    for (int k = 0; k < 3; ++k) {
        int m = set + 8 * k;
        const float* Wr; const float* Wi; int xm;
        if (m < MM) { Wr = w1r; Wi = w1i; xm = m; }
        else        { Wr = w2r; Wi = w2i; xm = m - MM; }
        float orr = 0.f, oii = 0.f;
        for (int i = 0; i < DV; ++i) {
            float gr = Fin[i][2 * m], gi = Fin[i][2 * m + 1];
            size_t wi = ((size_t)(l * DV + i) * DV + o) * (MM * MM) + xm * MM + ky;
            float wr = Wr[wi], wim = Wi[wi];
            orr += gr * wr - gi * wim;
            oii += gr * wim + gi * wr;
        }
        size_t off = ((((size_t)b * MM + ky) * DV + o) * MK + m) * 2;
        F[off] = orr * scale; F[off + 1] = oii * scale;
    }
}

// ----------------- pointwise: h = relu(conv1x1(h) + invDFT(F)), in place.
// block = (b,iy); builds the 3 KB g-row from F in-block (inverse iy-DFT with
// wave-uniform twiddles), then conv (weights staged in LDS, read as uniform
// b128 broadcasts) + inverse j-DFT per output channel.
template<int FINAL>
__global__ __launch_bounds__(256) void k_pt(float* __restrict__ h,
        const float* __restrict__ F, const float* __restrict__ ws_w,
        const float* __restrict__ ws_b, const float* __restrict__ q_w,
        const float* __restrict__ q_b, float* __restrict__ out, int l)
{
    __shared__ float gS[DV][MM * 2];   // [co][ky][2]
    __shared__ float wS[DV * DV];      // conv weights, 4 KB
    __shared__ float qS[DV];
    __shared__ float itw[MK * 2];      // e^{+i 2pi f_m iy/256}
    int tid = threadIdx.x;
    int b = blockIdx.x >> 8, iy = blockIdx.x & 255;

    const float* wsw = ws_w + (size_t)l * DV * DV;
    #pragma unroll
    for (int i = 0; i < 4; ++i)
        wS[tid + 256 * i] = wsw[tid + 256 * i];
    if (FINAL && tid < DV) qS[tid] = q_w[tid];
    if (tid < MK) {
        int f = (tid < MM) ? tid : (232 + tid);
        float ang = TWO_PI_N * (float)((f * iy) & 255);
        float s, c; sincosf(ang, &s, &c);
        itw[2 * tid] = c; itw[2 * tid + 1] = s;
    }

    float cs[MM], sn[MM];                      // e^{+i 2pi ky j/256}, j = tid
    #pragma unroll
    for (int ky = 0; ky < MM; ++ky) {
        float ang = TWO_PI_N * (float)((ky * tid) & 255);
        sincosf(ang, &sn[ky], &cs[ky]);
    }

    float* hb = h + ((size_t)b * DV * SS + iy) * SS + tid;
    float hval[DV];
    #pragma unroll
    for (int cc = 0; cc < DV; ++cc)
        hval[cc] = hb[(size_t)cc * SS * SS];
    __syncthreads();                            // itw, wS ready

    for (int idx = tid; idx < DV * MM; idx += 256) {
        int co = idx & 31, ky = idx >> 5;
        const float2* Fp = (const float2*)(F + ((((size_t)b * MM + ky) * DV + co) * MK) * 2);
        float gr = 0.f, gi = 0.f;
        #pragma unroll
        for (int m = 0; m < MK; ++m) {
            float2 fv = Fp[m];
            float ic = itw[2 * m], is = itw[2 * m + 1];
            gr += fv.x * ic - fv.y * is;        // F * e^{+i th}
            gi += fv.x * is + fv.y * ic;
        }
        gS[co][2 * ky] = gr; gS[co][2 * ky + 1] = gi;
    }
    __syncthreads();

    const float* wsb = ws_b + (size_t)l * DV;
    float oacc = FINAL ? q_b[0] : 0.f;

    #pragma unroll 4
    for (int co = 0; co < DV; ++co) {
        float acc = wsb[co];
        const float4* wp = (const float4*)&wS[co * DV];   // broadcast b128
        #pragma unroll
        for (int q = 0; q < 8; ++q) {
            float4 w4 = wp[q];
            acc += w4.x * hval[4*q]   + w4.y * hval[4*q+1]
                 + w4.z * hval[4*q+2] + w4.w * hval[4*q+3];
        }
        const float4* gp = (const float4*)&gS[co][0];     // broadcast b128
        #pragma unroll
        for (int q = 0; q < 6; ++q) {
            float4 gv = gp[q];
            acc += gv.x * cs[2*q]   - gv.y * sn[2*q];
            acc += gv.z * cs[2*q+1] - gv.w * sn[2*q+1];
        }
        if (FINAL) oacc += qS[co] * acc;
        else       hb[(size_t)co * SS * SS] = fmaxf(acc, 0.f);
    }
    if (FINAL) out[((size_t)b * SS + iy) * SS + tid] = oacc;
}

extern "C" void kernel_launch(void* const* d_in, const int* in_sizes, int n_in,
                              void* d_out, int out_size, void* d_ws, size_t ws_size,
                              hipStream_t stream)
{
    const float* x    = (const float*)d_in[0];
    const float* p_w  = (const float*)d_in[1];
    const float* p_b  = (const float*)d_in[2];
    const float* ws_w = (const float*)d_in[3];
    const float* ws_b = (const float*)d_in[4];
    const float* w1r  = (const float*)d_in[5];
    const float* w1i  = (const float*)d_in[6];
    const float* w2r  = (const float*)d_in[7];
    const float* w2i  = (const float*)d_in[8];
    const float* q_w  = (const float*)d_in[9];
    const float* q_b  = (const float*)d_in[10];
    float* out = (float*)d_out;

    float* h   = (float*)d_ws;
    float* A   = h + (size_t)NB * DV * SS * SS;
    float* F   = A + (size_t)NB * MM * DV * SS * 2;
    float* twT = F + (size_t)NB * MM * DV * MK * 2;

    dim3 blk(256);
    k_twinit<<<1, blk, 0, stream>>>(twT);
    k_lift<<<NB * SS, blk, 0, stream>>>(x, p_w, p_b, h);
    for (int l = 0; l < LL; ++l) {
        k_rowdft<<<NB * DV, blk, 0, stream>>>(h, twT, A);
        k_mix<<<NB * MM, blk, 0, stream>>>(A, w1r, w1i, w2r, w2i, F, l);
        if (l < LL - 1)
            k_pt<0><<<NB * SS, blk, 0, stream>>>(h, F, ws_w, ws_b,
                                                 nullptr, nullptr, nullptr, l);
        else
            k_pt<1><<<NB * SS, blk, 0, stream>>>(h, F, ws_w, ws_b,
                                                 q_w, q_b, out, l);
    }
}